// Round 1
// baseline (226.718 us; speedup 1.0000x reference)
//
#include <hip/hip_runtime.h>

#define PI2_64 0.098174770424681038f   // 2*pi/64

// Problem sizes (fixed): B=2, CI=CO=32, N=64, M=8
// Corner freq map: t in [0,16): f(t) = t (t<8) else 48+t  (i.e. 56..63)

// ---------------- A1: z-transform (64 z -> 8 kz), complex out ----------------
// grid 1024, block 256. Each block: 256 rows of 64 z. Row = (b,ci,x,y) flat.
// z1 layout: [row][kz][2]  (16 floats per row)
__global__ __launch_bounds__(256) void k_fwd_z(const float* __restrict__ x,
                                               float* __restrict__ z1) {
  __shared__ __align__(16) float lx[256 * 65];
  __shared__ float czs[64], szs[64];
  int tid = threadIdx.x;
  long base = (long)blockIdx.x * (256 * 64);
  const float4* xg = (const float4*)(x + base);
#pragma unroll
  for (int j = 0; j < 16; ++j) {
    int idx = j * 256 + tid;
    float4 v = xg[idx];
    int flat = idx << 2;
    int r = flat >> 6, c = flat & 63;
    float* dst = &lx[r * 65 + c];
    dst[0] = v.x; dst[1] = v.y; dst[2] = v.z; dst[3] = v.w;
  }
  if (tid < 64) {
    float s, c;
    __sincosf(-PI2_64 * (float)tid, &s, &c);
    czs[tid] = c; szs[tid] = s;
  }
  __syncthreads();

  float ar[8] = {0,0,0,0,0,0,0,0}, ai[8] = {0,0,0,0,0,0,0,0};
  const float* row = &lx[tid * 65];
  for (int z = 0; z < 64; ++z) {
    float xv = row[z];
    float bc = czs[z], bs = szs[z];      // e^{-i*2pi*z/64}
    float wr = 1.f, wi = 0.f;            // e^{-i*2pi*kz*z/64}, kz=0..7
#pragma unroll
    for (int k = 0; k < 8; ++k) {
      ar[k] = fmaf(xv, wr, ar[k]);
      ai[k] = fmaf(xv, wi, ai[k]);
      float nr = wr * bc - wi * bs;
      wi = wr * bs + wi * bc;
      wr = nr;
    }
  }
  float4* o = (float4*)(z1 + ((long)blockIdx.x * 256 + tid) * 16);
  o[0] = make_float4(ar[0], ai[0], ar[1], ai[1]);
  o[1] = make_float4(ar[2], ai[2], ar[3], ai[3]);
  o[2] = make_float4(ar[4], ai[4], ar[5], ai[5]);
  o[3] = make_float4(ar[6], ai[6], ar[7], ai[7]);
}

// ---------------- A2: y-transform (64 y -> 16 ky), complex -------------------
// grid 4096 (= B*CI*64 x-rows), block 128 = (ky 16)*(kz 8).
// z1 viewed [r2][y][kz][2]; z2 layout [r2][ky][kz][2]
__global__ __launch_bounds__(128) void k_fwd_y(const float* __restrict__ z1,
                                               float* __restrict__ z2) {
  __shared__ __align__(16) float s[64 * 16];
  int tid = threadIdx.x;
  const float4* src = (const float4*)(z1 + (long)blockIdx.x * 1024);
  float4* l4 = (float4*)s;
  l4[tid] = src[tid];
  l4[tid + 128] = src[tid + 128];
  __syncthreads();
  int ky = tid >> 3, kz = tid & 7;
  int f = (ky < 8) ? ky : 48 + ky;
  float bs, bc; __sincosf(-PI2_64 * (float)f, &bs, &bc);
  float wr = 1.f, wi = 0.f, accr = 0.f, acci = 0.f;
  for (int y = 0; y < 64; ++y) {
    float zr = s[y * 16 + kz * 2], zi = s[y * 16 + kz * 2 + 1];
    accr += zr * wr - zi * wi;
    acci += zr * wi + zi * wr;
    float nr = wr * bc - wi * bs;
    wi = wr * bs + wi * bc;
    wr = nr;
  }
  float2* o = (float2*)(z2 + (long)blockIdx.x * 256);
  o[tid] = make_float2(accr, acci);
}

// ---------------- A3: x-transform (64 x -> 16 t), REAL part only -------------
// grid 1024 (= B*CI * 16 u), block 128 = (t 16)*(v 8).
// z2 viewed [bi][x][ky][kz][2]; xc layout [bi][t][u][v] real
__global__ __launch_bounds__(128) void k_fwd_x(const float* __restrict__ z2,
                                               float* __restrict__ xc) {
  __shared__ __align__(16) float s[64 * 16];
  int tid = threadIdx.x;
  int bi = blockIdx.x >> 4;
  int u = blockIdx.x & 15;
  const float* src = z2 + (long)bi * 16384 + u * 16;
  {
    int xr = tid >> 1, c0 = (tid & 1) * 8;
    const float4* p = (const float4*)(src + xr * 256 + c0);
    float4* q = (float4*)(s + xr * 16 + c0);
    q[0] = p[0]; q[1] = p[1];
  }
  __syncthreads();
  int t = tid >> 3, v = tid & 7;
  int f = (t < 8) ? t : 48 + t;
  float bs, bc; __sincosf(-PI2_64 * (float)f, &bs, &bc);
  float wr = 1.f, wi = 0.f, acc = 0.f;
  for (int xx = 0; xx < 64; ++xx) {
    float zr = s[xx * 16 + v * 2], zi = s[xx * 16 + v * 2 + 1];
    acc += zr * wr - zi * wi;   // Re{ Z * e^{-i...} }
    float nr = wr * bc - wi * bs;
    wi = wr * bs + wi * bc;
    wr = nr;
  }
  xc[(long)bi * 2048 + t * 128 + u * 8 + v] = acc;
}

// ---------------- B: channel mix (CI -> CO per mode), real x * complex w -----
// grid 512 = (b 2)*(t 16)*(u 16), block 256 = (o 32)*(v 8)
// outm layout [b][o][t][u][v][2]
__global__ __launch_bounds__(256) void k_mix(const float* __restrict__ xc,
    const float* __restrict__ w1r, const float* __restrict__ w1i,
    const float* __restrict__ w2r, const float* __restrict__ w2i,
    const float* __restrict__ w3r, const float* __restrict__ w3i,
    const float* __restrict__ w4r, const float* __restrict__ w4i,
    float* __restrict__ outm) {
  __shared__ float sx[256];  // [i 32][v 8]
  int tid = threadIdx.x;
  int b = blockIdx.x >> 8;
  int t = (blockIdx.x >> 4) & 15;
  int u = blockIdx.x & 15;
  {
    int i = tid >> 3, v = tid & 7;
    sx[tid] = xc[(long)(b * 32 + i) * 2048 + t * 128 + u * 8 + v];
  }
  __syncthreads();
  const float* wr_ = (t < 8) ? ((u < 8) ? w1r : w3r) : ((u < 8) ? w2r : w4r);
  const float* wi_ = (t < 8) ? ((u < 8) ? w1i : w3i) : ((u < 8) ? w2i : w4i);
  int tm = t & 7, um = u & 7;
  int o = tid >> 3, v = tid & 7;
  long woff = (long)o * 512 + tm * 64 + um * 8 + v;
  float ar = 0.f, ai = 0.f;
#pragma unroll 4
  for (int i = 0; i < 32; ++i) {
    float xv = sx[i * 8 + v];
    ar = fmaf(xv, wr_[woff + (long)i * 16384], ar);
    ai = fmaf(xv, wi_[woff + (long)i * 16384], ai);
  }
  long oi = (long)(b * 32 + o) * 2048 + t * 128 + u * 8 + v;
  ((float2*)outm)[oi] = make_float2(ar, ai);
}

// ---------------- C1: inverse x expand (16 t -> 64 x), complex ---------------
// grid 1024 = (bo 64)*(u 16), block 512 = (x 64)*(v 8)
// y1 layout [bo][x][u][v][2]
__global__ __launch_bounds__(512) void k_inv_x(const float* __restrict__ outm,
                                               float* __restrict__ y1) {
  __shared__ float s[256];  // [t 16][v 8][2]
  int tid = threadIdx.x;
  int bo = blockIdx.x >> 4;
  int u = blockIdx.x & 15;
  if (tid < 256) {
    int t = tid >> 4, c = tid & 15;
    s[tid] = outm[(long)bo * 4096 + t * 256 + u * 16 + c];
  }
  __syncthreads();
  int xx = tid >> 3, v = tid & 7;
  float bs, bc; __sincosf(PI2_64 * (float)xx, &bs, &bc);  // e^{+i*2pi*x/64}
  float wr = 1.f, wi = 0.f, ar = 0.f, ai = 0.f;
#pragma unroll
  for (int t = 0; t < 8; ++t) {           // freqs 0..7
    float pr = s[t * 16 + v * 2], pi = s[t * 16 + v * 2 + 1];
    ar += pr * wr - pi * wi;
    ai += pr * wi + pi * wr;
    float nr = wr * bc - wi * bs; wi = wr * bs + wi * bc; wr = nr;
  }
  wi = -wi;                                // e^{+i*8...} -> conj = freq 56
#pragma unroll
  for (int t = 8; t < 16; ++t) {          // freqs 56..63
    float pr = s[t * 16 + v * 2], pi = s[t * 16 + v * 2 + 1];
    ar += pr * wr - pi * wi;
    ai += pr * wi + pi * wr;
    float nr = wr * bc - wi * bs; wi = wr * bs + wi * bc; wr = nr;
  }
  ((float2*)y1)[(long)bo * 8192 + xx * 128 + u * 8 + v] = make_float2(ar, ai);
}

// ---------------- C2: inverse y expand (16 u -> 64 y), complex ---------------
// grid 4096 = (bo 64)*(x 64), block 512 = (y 64)*(v 8)
// y2 layout [bo][x][y][v][2]
__global__ __launch_bounds__(512) void k_inv_y(const float* __restrict__ y1,
                                               float* __restrict__ y2) {
  __shared__ float s[256];  // [u 16][v 8][2]
  int tid = threadIdx.x;
  if (tid < 256) s[tid] = y1[(long)blockIdx.x * 256 + tid];
  __syncthreads();
  int yy = tid >> 3, v = tid & 7;
  float bs, bc; __sincosf(PI2_64 * (float)yy, &bs, &bc);
  float wr = 1.f, wi = 0.f, ar = 0.f, ai = 0.f;
#pragma unroll
  for (int u = 0; u < 8; ++u) {
    float pr = s[u * 16 + v * 2], pi = s[u * 16 + v * 2 + 1];
    ar += pr * wr - pi * wi;
    ai += pr * wi + pi * wr;
    float nr = wr * bc - wi * bs; wi = wr * bs + wi * bc; wr = nr;
  }
  wi = -wi;
#pragma unroll
  for (int u = 8; u < 16; ++u) {
    float pr = s[u * 16 + v * 2], pi = s[u * 16 + v * 2 + 1];
    ar += pr * wr - pi * wi;
    ai += pr * wi + pi * wr;
    float nr = wr * bc - wi * bs; wi = wr * bs + wi * bc; wr = nr;
  }
  ((float2*)y2)[(long)blockIdx.x * 512 + yy * 8 + v] = make_float2(ar, ai);
}

// ---------------- C3: inverse z expand (8 kz -> 64 z), real + scale ----------
// grid 4096 = (bo 64)*(x 64), block 256; thread: z = tid&63, y0 = tid>>6
__global__ __launch_bounds__(256) void k_inv_z(const float* __restrict__ y2,
                                               float* __restrict__ out) {
  __shared__ __align__(16) float s[64 * 16];  // [y][v 8][2]
  int tid = threadIdx.x;
  const float4* p4 = (const float4*)(y2 + (long)blockIdx.x * 1024);
  float4* l4 = (float4*)s;
  l4[tid] = p4[tid];
  __syncthreads();
  int z = tid & 63, y0 = tid >> 6;
  float bs, bc; __sincosf(PI2_64 * (float)z, &bs, &bc);  // e^{+i*2pi*z/64}
  float* o = out + (long)blockIdx.x * 4096;
  const float scale = 1.f / 262144.f;  // 1/64^3
  for (int yy = 0; yy < 16; ++yy) {
    int y = yy * 4 + y0;
    float wr = 1.f, wi = 0.f, acc = 0.f;
#pragma unroll
    for (int v = 0; v < 8; ++v) {
      float yr = s[y * 16 + v * 2], yi = s[y * 16 + v * 2 + 1];
      acc += yr * wr - yi * wi;   // Re{ Y * e^{+i...} }
      float nr = wr * bc - wi * bs; wi = wr * bs + wi * bc; wr = nr;
    }
    o[y * 64 + z] = acc * scale;
  }
}

extern "C" void kernel_launch(void* const* d_in, const int* in_sizes, int n_in,
                              void* d_out, int out_size, void* d_ws, size_t ws_size,
                              hipStream_t stream) {
  (void)in_sizes; (void)n_in; (void)out_size; (void)ws_size;
  const float* x   = (const float*)d_in[0];
  const float* w1r = (const float*)d_in[1];
  const float* w1i = (const float*)d_in[2];
  const float* w2r = (const float*)d_in[3];
  const float* w2i = (const float*)d_in[4];
  const float* w3r = (const float*)d_in[5];
  const float* w3i = (const float*)d_in[6];
  const float* w4r = (const float*)d_in[7];
  const float* w4i = (const float*)d_in[8];
  float* out = (float*)d_out;
  float* ws = (float*)d_ws;

  // workspace layout (floats), with aliasing: y1 reuses z2, y2 reuses z1
  float* z1   = ws;                 // 4,194,304 floats (16.8 MiB)
  float* z2   = ws + 4194304;       // 1,048,576 floats ( 4.2 MiB)
  float* xc   = ws + 5242880;       //   131,072 floats ( 0.5 MiB)
  float* outm = ws + 5373952;       //   262,144 floats ( 1.0 MiB)
  float* y1   = z2;                 // z2 dead after k_fwd_x
  float* y2   = z1;                 // z1 dead after k_fwd_y

  k_fwd_z<<<dim3(1024), dim3(256), 0, stream>>>(x, z1);
  k_fwd_y<<<dim3(4096), dim3(128), 0, stream>>>(z1, z2);
  k_fwd_x<<<dim3(1024), dim3(128), 0, stream>>>(z2, xc);
  k_mix<<<dim3(512), dim3(256), 0, stream>>>(xc, w1r, w1i, w2r, w2i,
                                             w3r, w3i, w4r, w4i, outm);
  k_inv_x<<<dim3(1024), dim3(512), 0, stream>>>(outm, y1);
  k_inv_y<<<dim3(4096), dim3(512), 0, stream>>>(y1, y2);
  k_inv_z<<<dim3(4096), dim3(256), 0, stream>>>(y2, out);
}

// Round 3
// 184.243 us; speedup vs baseline: 1.2305x; 1.2305x over previous
//
#include <hip/hip_runtime.h>

#define PI2_64 0.098174770424681038f   // 2*pi/64

// Sizes fixed: B=2, CI=CO=32, N=64, M=8. Corner freqs f(t)= t (t<8) else 48+t.
// Root table: rc[m]=cos(2*pi*m/64), rs[m]=sin(2*pi*m/64); e^{-i.}=(c,-s), e^{+i.}=(c,+s)

// ============ kA: fused forward z-DFT (64->8) + y-DFT (64->16) ==============
// grid 4096 = (b*32+ci)*64 + x ; block 256.
// out z2: [(bi*64+x)] * 128 float2, idx = ky*8+kz
__global__ __launch_bounds__(256) void k_fwd_zy(const float* __restrict__ x,
                                                float* __restrict__ z2) {
  __shared__ __align__(16) float sp[64 * 65];     // plane [y][z], pad 65
  __shared__ __align__(8) float2 Z[64 * 9];       // [y][kz], pad 9
  __shared__ float rc[64], rs[64];
  int tid = threadIdx.x;

  const float4* xg = (const float4*)(x + (long)blockIdx.x * 4096);
#pragma unroll
  for (int j = 0; j < 4; ++j) {
    int idx = j * 256 + tid;
    float4 v = xg[idx];
    int flat = idx << 2;
    int y = flat >> 6, z = flat & 63;
    float* d = &sp[y * 65 + z];
    d[0] = v.x; d[1] = v.y; d[2] = v.z; d[3] = v.w;
  }
  if (tid < 64) {
    float s, c; __sincosf(PI2_64 * (float)tid, &s, &c);
    rc[tid] = c; rs[tid] = s;
  }
  __syncthreads();

  // phase 1: z-DFT. thread = (y2 = tid>>3 in [0,32), kz = tid&7); rows y2, y2+32
  {
    int y2 = tid >> 3, kz = tid & 7;
    const float* r0 = &sp[y2 * 65];
    const float* r1 = &sp[(y2 + 32) * 65];
    float a0r = 0, a0i = 0, a1r = 0, a1i = 0;
    int m = 0;
#pragma unroll 4
    for (int z = 0; z < 64; ++z) {
      float c = rc[m], s = rs[m];
      float x0 = r0[z], x1 = r1[z];
      a0r = fmaf(x0, c, a0r); a0i = fmaf(-x0, s, a0i);
      a1r = fmaf(x1, c, a1r); a1i = fmaf(-x1, s, a1i);
      m = (m + kz) & 63;
    }
    Z[y2 * 9 + kz] = make_float2(a0r, a0i);
    Z[(y2 + 32) * 9 + kz] = make_float2(a1r, a1i);
  }
  __syncthreads();

  // phase 2: y-DFT. thread = (ky=(tid>>3)&15, kz=tid&7, h=tid>>7), 32 y each
  float2* pb = (float2*)sp;   // partials: [ky*9+kz] + 144*h  (sp is dead)
  {
    int kz = tid & 7, ky = (tid >> 3) & 15, h = tid >> 7;
    int f = (ky < 8) ? ky : (48 + ky);
    float ar = 0, ai = 0;
    int m = (h * 32 * f) & 63;
#pragma unroll 4
    for (int yy = h * 32; yy < h * 32 + 32; ++yy) {
      float2 zv = Z[yy * 9 + kz];
      float c = rc[m], s = rs[m];
      ar += zv.x * c + zv.y * s;     // * e^{-i th}
      ai += zv.y * c - zv.x * s;
      m = (m + f) & 63;
    }
    pb[ky * 9 + kz + 144 * h] = make_float2(ar, ai);
  }
  __syncthreads();
  if (tid < 128) {
    int kz = tid & 7, ky = tid >> 3;
    float2 a = pb[ky * 9 + kz], b = pb[ky * 9 + kz + 144];
    ((float2*)z2)[(long)blockIdx.x * 128 + tid] = make_float2(a.x + b.x, a.y + b.y);
  }
}

// ============ A3: x-transform (64 x -> 16 t), REAL part only ================
// grid 1024 (= B*CI * 16 u), block 128 = (t 16)*(v 8).
__global__ __launch_bounds__(128) void k_fwd_x(const float* __restrict__ z2,
                                               float* __restrict__ xc) {
  __shared__ __align__(16) float s[64 * 16];
  int tid = threadIdx.x;
  int bi = blockIdx.x >> 4;
  int u = blockIdx.x & 15;
  const float* src = z2 + (long)bi * 16384 + u * 16;
  {
    int xr = tid >> 1, c0 = (tid & 1) * 8;
    const float4* p = (const float4*)(src + xr * 256 + c0);
    float4* q = (float4*)(s + xr * 16 + c0);
    q[0] = p[0]; q[1] = p[1];
  }
  __syncthreads();
  int t = tid >> 3, v = tid & 7;
  int f = (t < 8) ? t : 48 + t;
  float bs, bc; __sincosf(-PI2_64 * (float)f, &bs, &bc);
  float wr = 1.f, wi = 0.f, acc = 0.f;
  for (int xx = 0; xx < 64; ++xx) {
    float zr = s[xx * 16 + v * 2], zi = s[xx * 16 + v * 2 + 1];
    acc += zr * wr - zi * wi;   // Re{ Z * e^{-i...} }
    float nr = wr * bc - wi * bs;
    wi = wr * bs + wi * bc;
    wr = nr;
  }
  xc[(long)bi * 2048 + t * 128 + u * 8 + v] = acc;
}

// ============ B: channel mix (CI -> CO per mode) ============================
// grid 512 = (b 2)*(t 16)*(u 16), block 256 = (o 32)*(v 8)
__global__ __launch_bounds__(256) void k_mix(const float* __restrict__ xc,
    const float* __restrict__ w1r, const float* __restrict__ w1i,
    const float* __restrict__ w2r, const float* __restrict__ w2i,
    const float* __restrict__ w3r, const float* __restrict__ w3i,
    const float* __restrict__ w4r, const float* __restrict__ w4i,
    float* __restrict__ outm) {
  __shared__ float sx[256];  // [i 32][v 8]
  int tid = threadIdx.x;
  int b = blockIdx.x >> 8;
  int t = (blockIdx.x >> 4) & 15;
  int u = blockIdx.x & 15;
  {
    int i = tid >> 3, v = tid & 7;
    sx[tid] = xc[(long)(b * 32 + i) * 2048 + t * 128 + u * 8 + v];
  }
  __syncthreads();
  const float* wr_ = (t < 8) ? ((u < 8) ? w1r : w3r) : ((u < 8) ? w2r : w4r);
  const float* wi_ = (t < 8) ? ((u < 8) ? w1i : w3i) : ((u < 8) ? w2i : w4i);
  int tm = t & 7, um = u & 7;
  int o = tid >> 3, v = tid & 7;
  long woff = (long)o * 512 + tm * 64 + um * 8 + v;
  float ar = 0.f, ai = 0.f;
#pragma unroll 4
  for (int i = 0; i < 32; ++i) {
    float xv = sx[i * 8 + v];
    ar = fmaf(xv, wr_[woff + (long)i * 16384], ar);
    ai = fmaf(xv, wi_[woff + (long)i * 16384], ai);
  }
  long oi = (long)(b * 32 + o) * 2048 + t * 128 + u * 8 + v;
  ((float2*)outm)[oi] = make_float2(ar, ai);
}

// ============ kC: fused inverse x (16->64) + y (16->64) + z (8->64,Re) ======
// grid 4096 = bo*64 + x ; block 256. reads outm[bo] (16KB), writes out plane.
__global__ __launch_bounds__(256) void k_inv_xyz(const float* __restrict__ outm,
                                                 float* __restrict__ out) {
  __shared__ __align__(8) float2 P[16 * 16 * 9];  // [t][u][v pad9]
  __shared__ __align__(8) float2 Y2[64 * 9];      // [y][v pad9]; also C1 partials
  __shared__ __align__(8) float2 Y1[16 * 9];      // [u][v pad9]
  __shared__ float rc[64], rs[64];
  int tid = threadIdx.x;
  int bo = blockIdx.x >> 6, xx = blockIdx.x & 63;

  const float2* pg = (const float2*)(outm + (long)bo * 4096);
#pragma unroll
  for (int j = 0; j < 8; ++j) {
    int k = j * 256 + tid;          // float2 idx = (t*16+u)*8 + v
    int v = k & 7, tu = k >> 3;
    P[tu * 9 + v] = pg[k];
  }
  if (tid < 64) {
    float s, c; __sincosf(PI2_64 * (float)tid, &s, &c);
    rc[tid] = c; rs[tid] = s;
  }
  __syncthreads();

  // C1: x-expand at this xx. thread = (u=(tid>>3)&15, v=tid&7, h=tid>>7)
  float2* pb = Y2;   // partials [u*9+v] + 144*h
  {
    int v = tid & 7, u = (tid >> 3) & 15, h = tid >> 7;
    float ar = 0, ai = 0;
#pragma unroll
    for (int t = h * 8; t < h * 8 + 8; ++t) {
      int f = (t < 8) ? t : (48 + t);
      int m = (f * xx) & 63;
      float2 p = P[(t * 16 + u) * 9 + v];
      float c = rc[m], s = rs[m];
      ar += p.x * c - p.y * s;       // * e^{+i th}
      ai += p.y * c + p.x * s;
    }
    pb[u * 9 + v + 144 * h] = make_float2(ar, ai);
  }
  __syncthreads();
  if (tid < 128) {
    int v = tid & 7, u = tid >> 3;
    float2 a = pb[u * 9 + v], b = pb[u * 9 + v + 144];
    Y1[u * 9 + v] = make_float2(a.x + b.x, a.y + b.y);
  }
  __syncthreads();

  // C2: y-expand. thread = (y0=tid>>3 in [0,32), v=tid&7); rows y0, y0+32
  {
    int v = tid & 7, y0 = tid >> 3;
    int ya = y0, yb = y0 + 32;
    float ar0 = 0, ai0 = 0, ar1 = 0, ai1 = 0;
#pragma unroll
    for (int u = 0; u < 16; ++u) {
      int f = (u < 8) ? u : (48 + u);
      float2 q = Y1[u * 9 + v];
      int ma = (f * ya) & 63, mb = (f * yb) & 63;
      float ca = rc[ma], sa = rs[ma];
      float cb = rc[mb], sb = rs[mb];
      ar0 += q.x * ca - q.y * sa; ai0 += q.y * ca + q.x * sa;
      ar1 += q.x * cb - q.y * sb; ai1 += q.y * cb + q.x * sb;
    }
    __syncthreads();   // everyone done reading pb(Y2) region from C1 combine
    Y2[ya * 9 + v] = make_float2(ar0, ai0);
    Y2[yb * 9 + v] = make_float2(ar1, ai1);
  }
  __syncthreads();

  // C3: z-expand + Re + scale. thread = (y0=tid>>4 in [0,16), zq=tid&15)
  {
    int zq = tid & 15, y0 = tid >> 4;
    int z0 = zq * 4;
    const float sc = 1.f / 262144.f;   // 1/64^3
    float acc[4][4] = {{0,0,0,0},{0,0,0,0},{0,0,0,0},{0,0,0,0}};
#pragma unroll
    for (int v = 0; v < 8; ++v) {
      int m0 = (v * z0) & 63, m1 = (m0 + v) & 63, m2 = (m1 + v) & 63, m3 = (m2 + v) & 63;
      float c0 = rc[m0], s0 = rs[m0], c1 = rc[m1], s1 = rs[m1];
      float c2 = rc[m2], s2 = rs[m2], c3 = rc[m3], s3 = rs[m3];
#pragma unroll
      for (int yo = 0; yo < 4; ++yo) {
        float2 q = Y2[(y0 + yo * 16) * 9 + v];
        acc[yo][0] += q.x * c0 - q.y * s0;
        acc[yo][1] += q.x * c1 - q.y * s1;
        acc[yo][2] += q.x * c2 - q.y * s2;
        acc[yo][3] += q.x * c3 - q.y * s3;
      }
    }
    float* ob = out + (long)blockIdx.x * 4096;
#pragma unroll
    for (int yo = 0; yo < 4; ++yo) {
      int y = y0 + yo * 16;
      ((float4*)(ob + y * 64 + z0))[0] =
          make_float4(acc[yo][0] * sc, acc[yo][1] * sc, acc[yo][2] * sc, acc[yo][3] * sc);
    }
  }
}

extern "C" void kernel_launch(void* const* d_in, const int* in_sizes, int n_in,
                              void* d_out, int out_size, void* d_ws, size_t ws_size,
                              hipStream_t stream) {
  (void)in_sizes; (void)n_in; (void)out_size; (void)ws_size;
  const float* x   = (const float*)d_in[0];
  const float* w1r = (const float*)d_in[1];
  const float* w1i = (const float*)d_in[2];
  const float* w2r = (const float*)d_in[3];
  const float* w2i = (const float*)d_in[4];
  const float* w3r = (const float*)d_in[5];
  const float* w3i = (const float*)d_in[6];
  const float* w4r = (const float*)d_in[7];
  const float* w4i = (const float*)d_in[8];
  float* out = (float*)d_out;
  float* ws = (float*)d_ws;

  float* z2   = ws;                 // 1,048,576 floats (4.2 MiB)
  float* xc   = ws + 1048576;       //   131,072 floats
  float* outm = ws + 1179648;       //   262,144 floats

  k_fwd_zy <<<dim3(4096), dim3(256), 0, stream>>>(x, z2);
  k_fwd_x  <<<dim3(1024), dim3(128), 0, stream>>>(z2, xc);
  k_mix    <<<dim3(512),  dim3(256), 0, stream>>>(xc, w1r, w1i, w2r, w2i,
                                                  w3r, w3i, w4r, w4i, outm);
  k_inv_xyz<<<dim3(4096), dim3(256), 0, stream>>>(outm, out);
}